// Round 1
// baseline (251.257 us; speedup 1.0000x reference)
//
#include <hip/hip_runtime.h>
#include <math.h>

#define D 128

typedef __attribute__((ext_vector_type(8))) short bf16x8;
typedef __attribute__((ext_vector_type(4))) float f32x4;

__device__ __forceinline__ unsigned int bf16_round(float f) {
  unsigned int u = __float_as_uint(f);
  return (u + 0x7fffu + ((u >> 16) & 1u)) >> 16;  // RNE
}
__device__ __forceinline__ float bf_lo(unsigned int u) { return __uint_as_float(u << 16); }
__device__ __forceinline__ float bf_hi(unsigned int u) { return __uint_as_float(u & 0xffff0000u); }

// Fused role-split kernel (Bresenham-interleaved so both roles are co-resident):
//  - hist blocks: fire-and-forget atomicAdd(cnt[tgt[e]]) (no rank, no return wait)
//  - pq blocks:   p/q dots + xbh=bf16(x) + (first 64) wt=bf16(W^T)  (BW-bound)
__global__ __launch_bounds__(256) void k_pre(const float* __restrict__ x,
                                             const float* __restrict__ w_pred,
                                             const float* __restrict__ W,
                                             const int* __restrict__ tgt,
                                             float* __restrict__ p, float* __restrict__ q,
                                             unsigned int* __restrict__ xbh,
                                             unsigned short* __restrict__ wt,
                                             int* __restrict__ cnt,
                                             int n, int E, int nbHist, int total) {
  int bid = blockIdx.x;
  long long h0 = (long long)bid * nbHist / total;
  long long h1 = (long long)(bid + 1) * nbHist / total;
  if (h1 != h0) {
    // ---- hist role: single-copy count, no return value needed ----
    int e = (int)h0 * 256 + threadIdx.x;
    if (e < E) atomicAdd(&cnt[tgt[e]], 1);
    return;
  }
  // ---- pq role ----
  int pqIdx = bid - (int)h1;
  int ptid = pqIdx * 256 + threadIdx.x;
  if (ptid < 16384) {  // W transpose -> bf16 (first 64 pq blocks)
    int col = ptid >> 7, k = ptid & 127;
    wt[col * 128 + k] = (unsigned short)bf16_round(W[k * 128 + col]);
  }
  int wid = ptid >> 6;
  int lane = threadIdx.x & 63;
  if (wid >= n) return;
  float2 xv = ((const float2*)(x + (size_t)wid * D))[lane];
  xbh[(size_t)wid * 64 + lane] = bf16_round(xv.x) | (bf16_round(xv.y) << 16);
  float2 wp = ((const float2*)w_pred)[lane];
  float2 wq = ((const float2*)w_pred)[64 + lane];
  float pp = xv.x * wp.x + xv.y * wp.y;
  float qq = xv.x * wq.x + xv.y * wq.y;
#pragma unroll
  for (int off = 32; off > 0; off >>= 1) {
    pp += __shfl_down(pp, off);
    qq += __shfl_down(qq, off);
  }
  if (lane == 0) { p[wid] = pp; q[wid] = qq; }
}

// scan1: block-scan 1024 elements of the single-copy cnt -> rowptr partial + bsum
__global__ __launch_bounds__(256) void k_scan1(const int* __restrict__ cnt,
                                               int* __restrict__ rowptr,
                                               int* __restrict__ bsum, int n) {
  __shared__ int wsum[4];
  int base = blockIdx.x * 1024 + threadIdx.x * 4;
  int4 v = make_int4(0, 0, 0, 0);
  if (base + 3 < n) {
    v = *(const int4*)(cnt + base);
  } else {
    if (base + 0 < n) v.x = cnt[base + 0];
    if (base + 1 < n) v.y = cnt[base + 1];
    if (base + 2 < n) v.z = cnt[base + 2];
    if (base + 3 < n) v.w = cnt[base + 3];
  }
  int s = v.x + v.y + v.z + v.w;
  int lane = threadIdx.x & 63;
  int wave = threadIdx.x >> 6;
  int incl = s;
#pragma unroll
  for (int off = 1; off < 64; off <<= 1) {
    int t = __shfl_up(incl, off);
    if (lane >= off) incl += t;
  }
  if (lane == 63) wsum[wave] = incl;
  __syncthreads();
  int woff = 0;
#pragma unroll
  for (int w = 0; w < 4; ++w) if (w < wave) woff += wsum[w];
  int excl = woff + incl - s;
  if (base + 0 < n) rowptr[base + 0] = excl;
  if (base + 1 < n) rowptr[base + 1] = excl + v.x;
  if (base + 2 < n) rowptr[base + 2] = excl + v.x + v.y;
  if (base + 3 < n) rowptr[base + 3] = excl + v.x + v.y + v.z;
  if (threadIdx.x == 255) bsum[blockIdx.x] = woff + incl;
}

// cursors: wave 0 scans bsum; finalize rowptr; single cursor copy = rowptr
__global__ __launch_bounds__(256) void k_cursors(int* __restrict__ rowptr,
                                                 const int* __restrict__ bsum,
                                                 int* __restrict__ cursor,
                                                 int n, int E, int nb) {
  __shared__ int bpre_s[64];
  if (threadIdx.x < 64) {
    int lane = threadIdx.x;
    int v = (lane < nb) ? bsum[lane] : 0;
    int incl = v;
#pragma unroll
    for (int off = 1; off < 64; off <<= 1) {
      int t = __shfl_up(incl, off);
      if (lane >= off) incl += t;
    }
    bpre_s[lane] = incl - v;
  }
  __syncthreads();
  int t = blockIdx.x * blockDim.x + threadIdx.x;
  if (t < n) {
    int r = rowptr[t] + bpre_s[t >> 10];
    rowptr[t] = r;
    cursor[t] = r;
  }
  if (t == 0) rowptr[n] = E;
}

// fill: ew = sigmoid(p[s]+q[t]+b); slot via returning atomic on L2-resident
// cursor; weighted degree via fire-and-forget float atomic on degw.
// edata[pos] = (src:u16 | bf16(ew)<<16)  -- 4B packed record
__global__ __launch_bounds__(256) void k_fill(const int* __restrict__ src,
                                              const int* __restrict__ tgt,
                                              int* __restrict__ cursor,
                                              const float* __restrict__ p,
                                              const float* __restrict__ q,
                                              const float* __restrict__ b_pred,
                                              unsigned int* __restrict__ edata,
                                              float* __restrict__ degw,
                                              int E, int n) {
  int e = blockIdx.x * blockDim.x + threadIdx.x;
  if (e >= E) return;
  int s = src[e], t = tgt[e];
  float z = p[s] + q[t] + b_pred[0];
  float w = 1.0f / (1.0f + expf(-z));
  int pos = atomicAdd(&cursor[t], 1);
  edata[pos] = (unsigned int)s | (bf16_round(w) << 16);  // n < 65536 fits u16
  atomicAdd(&degw[t], w);
}

// MFMA GEMM + fused dis: dis[row] = rsqrt(1 + degw[row]) (precomputed sum, no
// seg-sum latency chain), then xwh = bf16( dis[row] * (xbh @ W) ).
__global__ __launch_bounds__(256) void k_gemm_mfma(const short* __restrict__ xbh,
                                                   const short* __restrict__ wt,
                                                   const float* __restrict__ degw,
                                                   float* __restrict__ dis,
                                                   unsigned int* __restrict__ xwh, int n) {
  __shared__ float cbuf[4][16 * 128];  // 32 KB
  int wave = threadIdx.x >> 6;
  int lane = threadIdx.x & 63;
  int row0 = blockIdx.x * 64 + wave * 16;

  // ---- dis for this wave's 16 rows (4 lanes per row, broadcast read) ----
  int rr = lane >> 2, jj = lane & 3;
  int grow = row0 + rr;
  float dv = 0.0f;
  if (grow < n) {
    float d = 1.0f + degw[grow];
    dv = (d > 0.0f) ? rsqrtf(d) : 0.0f;
    if (jj == 0) dis[grow] = dv;
  }

  // ---- MFMA ----
  int rA = lane & 15, quad = lane >> 4;
  f32x4 acc[8];
#pragma unroll
  for (int cb = 0; cb < 8; ++cb) acc[cb] = (f32x4){0.f, 0.f, 0.f, 0.f};

  const short* arow = xbh + (size_t)(row0 + rA) * 128 + quad * 8;
  bool arow_ok = (row0 + rA) < n;
#pragma unroll
  for (int kk = 0; kk < 4; ++kk) {
    bf16x8 a;
    if (arow_ok) a = *(const bf16x8*)(arow + kk * 32);
    else a = (bf16x8){0, 0, 0, 0, 0, 0, 0, 0};
#pragma unroll
    for (int cb = 0; cb < 8; ++cb) {
      bf16x8 bf = *(const bf16x8*)(wt + (size_t)(cb * 16 + rA) * 128 + kk * 32 + quad * 8);
      acc[cb] = __builtin_amdgcn_mfma_f32_16x16x32_bf16(a, bf, acc[cb], 0, 0, 0);
    }
  }

  // C/D layout: col = cb*16 + (lane&15), row = quad*4 + reg
#pragma unroll
  for (int cb = 0; cb < 8; ++cb)
#pragma unroll
    for (int r = 0; r < 4; ++r)
      cbuf[wave][(quad * 4 + r) * 128 + cb * 16 + rA] = acc[cb][r];
  __syncthreads();

  int ch = jj * 32;                // col chunk of 32 (jj = lane&3)
  if (grow < n) {
    const float* cr = &cbuf[wave][rr * 128 + ch];
#pragma unroll
    for (int g = 0; g < 2; ++g) {  // 2 x 16 cols -> 2 x uint4
      uint4 o;
      o.x = bf16_round(cr[g * 16 + 0] * dv)  | (bf16_round(cr[g * 16 + 1] * dv) << 16);
      o.y = bf16_round(cr[g * 16 + 2] * dv)  | (bf16_round(cr[g * 16 + 3] * dv) << 16);
      o.z = bf16_round(cr[g * 16 + 4] * dv)  | (bf16_round(cr[g * 16 + 5] * dv) << 16);
      o.w = bf16_round(cr[g * 16 + 6] * dv)  | (bf16_round(cr[g * 16 + 7] * dv) << 16);
      uint4 o2;
      o2.x = bf16_round(cr[g * 16 + 8] * dv)  | (bf16_round(cr[g * 16 + 9] * dv) << 16);
      o2.y = bf16_round(cr[g * 16 + 10] * dv) | (bf16_round(cr[g * 16 + 11] * dv) << 16);
      o2.z = bf16_round(cr[g * 16 + 12] * dv) | (bf16_round(cr[g * 16 + 13] * dv) << 16);
      o2.w = bf16_round(cr[g * 16 + 14] * dv) | (bf16_round(cr[g * 16 + 15] * dv) << 16);
      *(uint4*)(xwh + (size_t)grow * 64 + (ch >> 1) + g * 8)     = o;
      *(uint4*)(xwh + (size_t)grow * 64 + (ch >> 1) + g * 8 + 4) = o2;
    }
  }
}

// One wave per node; lane = (rg in [0,4), cj in [0,16)). ILP-batched: per
// 16-edge group, all 4 shuffle-extracts and all 4 scattered uint4 loads issue
// before the FMA block (R11 profile showed VGPR=20 -> serial load-use chain).
__global__ __launch_bounds__(256) void k_gather(const int* __restrict__ rowptr,
                                                const unsigned int* __restrict__ edata,
                                                const uint4* __restrict__ xwh4,
                                                const float* __restrict__ dis,
                                                const float* __restrict__ b,
                                                float* __restrict__ out, int n) {
  int wid = (blockIdx.x * blockDim.x + threadIdx.x) >> 6;
  int lane = threadIdx.x & 63;
  if (wid >= n) return;
  int cj = lane & 15;
  int rg = lane >> 4;
  int2 rp = *(const int2*)(rowptr + wid);
  int beg = rp.x, end = rp.y;

  float acc[8];
  if (rg == 0) {  // self-loop term, counted once
    uint4 v = xwh4[(size_t)wid * 16 + cj];
    acc[0] = bf_lo(v.x); acc[1] = bf_hi(v.x);
    acc[2] = bf_lo(v.y); acc[3] = bf_hi(v.y);
    acc[4] = bf_lo(v.z); acc[5] = bf_hi(v.z);
    acc[6] = bf_lo(v.w); acc[7] = bf_hi(v.w);
  } else {
#pragma unroll
    for (int i = 0; i < 8; ++i) acc[i] = 0.0f;
  }

  for (int j0 = beg; j0 < end; j0 += 64) {
    int m = end - j0; if (m > 64) m = 64;
    unsigned int wl = 0;
    if (lane < m) wl = edata[j0 + lane];
    for (int k = 0; k < m; k += 16) {
      // extract 4 records (independent shfls), zero-guard tails
      unsigned int w0 = (unsigned int)__shfl((int)wl, k + rg);
      unsigned int w1 = (unsigned int)__shfl((int)wl, k + 4 + rg);
      unsigned int w2 = (unsigned int)__shfl((int)wl, k + 8 + rg);
      unsigned int w3 = (unsigned int)__shfl((int)wl, k + 12 + rg);
      if (k + rg >= m)      w0 = 0;  // s=0, c=+0.0 -> harmless
      if (k + 4 + rg >= m)  w1 = 0;
      if (k + 8 + rg >= m)  w2 = 0;
      if (k + 12 + rg >= m) w3 = 0;
      // issue all 4 scattered loads back-to-back (overlapping latencies)
      uint4 v0 = xwh4[(size_t)(w0 & 0xffffu) * 16 + cj];
      uint4 v1 = xwh4[(size_t)(w1 & 0xffffu) * 16 + cj];
      uint4 v2 = xwh4[(size_t)(w2 & 0xffffu) * 16 + cj];
      uint4 v3 = xwh4[(size_t)(w3 & 0xffffu) * 16 + cj];
      float c0 = bf_hi(w0), c1 = bf_hi(w1), c2 = bf_hi(w2), c3 = bf_hi(w3);
      acc[0] = fmaf(c0, bf_lo(v0.x), acc[0]); acc[1] = fmaf(c0, bf_hi(v0.x), acc[1]);
      acc[2] = fmaf(c0, bf_lo(v0.y), acc[2]); acc[3] = fmaf(c0, bf_hi(v0.y), acc[3]);
      acc[4] = fmaf(c0, bf_lo(v0.z), acc[4]); acc[5] = fmaf(c0, bf_hi(v0.z), acc[5]);
      acc[6] = fmaf(c0, bf_lo(v0.w), acc[6]); acc[7] = fmaf(c0, bf_hi(v0.w), acc[7]);
      acc[0] = fmaf(c1, bf_lo(v1.x), acc[0]); acc[1] = fmaf(c1, bf_hi(v1.x), acc[1]);
      acc[2] = fmaf(c1, bf_lo(v1.y), acc[2]); acc[3] = fmaf(c1, bf_hi(v1.y), acc[3]);
      acc[4] = fmaf(c1, bf_lo(v1.z), acc[4]); acc[5] = fmaf(c1, bf_hi(v1.z), acc[5]);
      acc[6] = fmaf(c1, bf_lo(v1.w), acc[6]); acc[7] = fmaf(c1, bf_hi(v1.w), acc[7]);
      acc[0] = fmaf(c2, bf_lo(v2.x), acc[0]); acc[1] = fmaf(c2, bf_hi(v2.x), acc[1]);
      acc[2] = fmaf(c2, bf_lo(v2.y), acc[2]); acc[3] = fmaf(c2, bf_hi(v2.y), acc[3]);
      acc[4] = fmaf(c2, bf_lo(v2.z), acc[4]); acc[5] = fmaf(c2, bf_hi(v2.z), acc[5]);
      acc[6] = fmaf(c2, bf_lo(v2.w), acc[6]); acc[7] = fmaf(c2, bf_hi(v2.w), acc[7]);
      acc[0] = fmaf(c3, bf_lo(v3.x), acc[0]); acc[1] = fmaf(c3, bf_hi(v3.x), acc[1]);
      acc[2] = fmaf(c3, bf_lo(v3.y), acc[2]); acc[3] = fmaf(c3, bf_hi(v3.y), acc[3]);
      acc[4] = fmaf(c3, bf_lo(v3.z), acc[4]); acc[5] = fmaf(c3, bf_hi(v3.z), acc[5]);
      acc[6] = fmaf(c3, bf_lo(v3.w), acc[6]); acc[7] = fmaf(c3, bf_hi(v3.w), acc[7]);
    }
  }

#pragma unroll
  for (int i = 0; i < 8; ++i) {
    acc[i] += __shfl_xor(acc[i], 16);
    acc[i] += __shfl_xor(acc[i], 32);
  }

  if (rg == 0) {
    float dt = dis[wid];
    float4 b0 = ((const float4*)b)[cj * 2];
    float4 b1 = ((const float4*)b)[cj * 2 + 1];
    float4 o0, o1;
    o0.x = fmaf(dt, acc[0], b0.x); o0.y = fmaf(dt, acc[1], b0.y);
    o0.z = fmaf(dt, acc[2], b0.z); o0.w = fmaf(dt, acc[3], b0.w);
    o1.x = fmaf(dt, acc[4], b1.x); o1.y = fmaf(dt, acc[5], b1.y);
    o1.z = fmaf(dt, acc[6], b1.z); o1.w = fmaf(dt, acc[7], b1.w);
    ((float4*)out)[(size_t)wid * 32 + cj * 2] = o0;
    ((float4*)out)[(size_t)wid * 32 + cj * 2 + 1] = o1;
  }
}

extern "C" void kernel_launch(void* const* d_in, const int* in_sizes, int n_in,
                              void* d_out, int out_size, void* d_ws, size_t ws_size,
                              hipStream_t stream) {
  const float* x      = (const float*)d_in[0];
  const int*   ei     = (const int*)d_in[1];
  const float* W      = (const float*)d_in[2];
  const float* b      = (const float*)d_in[3];
  const float* w_pred = (const float*)d_in[4];
  const float* b_pred = (const float*)d_in[5];

  int n = in_sizes[0] / D;
  int E = in_sizes[1] / 2;
  const int* src = ei;       // edge_index[0]
  const int* tgt = ei + E;   // edge_index[1]

  float* out = (float*)d_out;
  float* ws  = (float*)d_ws;
  // workspace layout (4B words)
  unsigned int* xwh = (unsigned int*)ws;           // n*64 (bf16 pairs)
  unsigned int* xbh = xwh + (size_t)n * 64;        // n*64 (bf16 pairs of x)
  float* p       = (float*)(xbh + (size_t)n * 64); // n
  float* q       = p + n;                          // n
  float* dis     = q + n;                          // n
  unsigned int* edata = (unsigned int*)(dis + n);  // E packed (src|ew)
  float* degw    = (float*)(edata + E);            // n  (zeroed)
  int*   cnt     = (int*)(degw + n);               // n  (zeroed, contiguous w/ degw)
  int*   cursor  = cnt + n;                        // n
  int*   rowptr  = cursor + n;                     // n+1
  int*   bsum    = rowptr + n + 1;                 // 64
  unsigned short* wt = (unsigned short*)(bsum + 64);  // 16384 shorts

  int nb = (n + 1023) / 1024;     // scan blocks (<=64 for n<=65536)
  int nbPq = (n + 3) / 4;
  int nbHist = (E + 255) / 256;
  int total = nbPq + nbHist;

  (void)hipMemsetAsync(degw, 0, (size_t)2 * n * sizeof(int), stream);  // degw + cnt
  k_pre<<<total, 256, 0, stream>>>(x, w_pred, W, tgt, p, q, xbh, wt, cnt,
                                   n, E, nbHist, total);
  k_scan1<<<nb, 256, 0, stream>>>(cnt, rowptr, bsum, n);
  k_cursors<<<(n + 255) / 256, 256, 0, stream>>>(rowptr, bsum, cursor, n, E, nb);
  k_fill<<<(E + 255) / 256, 256, 0, stream>>>(src, tgt, cursor, p, q, b_pred, edata, degw, E, n);
  k_gemm_mfma<<<(n + 63) / 64, 256, 0, stream>>>((const short*)xbh, (const short*)wt,
                                                 degw, dis, xwh, n);
  k_gather<<<(n + 3) / 4, 256, 0, stream>>>(rowptr, edata, (const uint4*)xwh, dis, b, out, n);
}

// Round 2
// 225.842 us; speedup vs baseline: 1.1125x; 1.1125x over previous
//
#include <hip/hip_runtime.h>
#include <math.h>

#define D 128
#define NC 32   // privatized histogram copies

typedef __attribute__((ext_vector_type(8))) short bf16x8;
typedef __attribute__((ext_vector_type(4))) float f32x4;

__device__ __forceinline__ unsigned int bf16_round(float f) {
  unsigned int u = __float_as_uint(f);
  return (u + 0x7fffu + ((u >> 16) & 1u)) >> 16;  // RNE
}
__device__ __forceinline__ float bf_lo(unsigned int u) { return __uint_as_float(u << 16); }
__device__ __forceinline__ float bf_hi(unsigned int u) { return __uint_as_float(u & 0xffff0000u); }

// Fused role-split kernel (Bresenham-interleaved so both roles are co-resident):
//  - hist blocks: rank[e] = atomicAdd(partial[c][tgt[e]], 1)   (latency-bound,
//    hidden under the BW-bound pq role running on the same CUs)
//  - pq blocks:   p/q dots + xbh=bf16(x) + (first 64) wt=bf16(W^T)  (BW-bound)
__global__ __launch_bounds__(256) void k_pre(const float* __restrict__ x,
                                             const float* __restrict__ w_pred,
                                             const float* __restrict__ W,
                                             const int* __restrict__ tgt,
                                             float* __restrict__ p, float* __restrict__ q,
                                             unsigned int* __restrict__ xbh,
                                             unsigned short* __restrict__ wt,
                                             int* __restrict__ rank,
                                             int* __restrict__ partial,
                                             int n, int E, int nbHist, int total) {
  int bid = blockIdx.x;
  long long h0 = (long long)bid * nbHist / total;
  long long h1 = (long long)(bid + 1) * nbHist / total;
  if (h1 != h0) {
    // ---- hist role ----
    int e = (int)h0 * 256 + threadIdx.x;
    if (e < E) {
      int t = tgt[e];
      int c = (e >> 8) & (NC - 1);
      rank[e] = atomicAdd(&partial[c * n + t], 1);
    }
    return;
  }
  // ---- pq role ----
  int pqIdx = bid - (int)h1;
  int ptid = pqIdx * 256 + threadIdx.x;
  if (ptid < 16384) {  // W transpose -> bf16 (first 64 pq blocks)
    int col = ptid >> 7, k = ptid & 127;
    wt[col * 128 + k] = (unsigned short)bf16_round(W[k * 128 + col]);
  }
  int wid = ptid >> 6;
  int lane = threadIdx.x & 63;
  if (wid >= n) return;
  float2 xv = ((const float2*)(x + (size_t)wid * D))[lane];
  xbh[(size_t)wid * 64 + lane] = bf16_round(xv.x) | (bf16_round(xv.y) << 16);
  float2 wp = ((const float2*)w_pred)[lane];
  float2 wq = ((const float2*)w_pred)[64 + lane];
  float pp = xv.x * wp.x + xv.y * wp.y;
  float qq = xv.x * wq.x + xv.y * wq.y;
#pragma unroll
  for (int off = 32; off > 0; off >>= 1) {
    pp += __shfl_down(pp, off);
    qq += __shfl_down(qq, off);
  }
  if (lane == 0) { p[wid] = pp; q[wid] = qq; }
}

// scan1 (fused reduce): cnt[t]=sum_c partial[c][t]; block-scan 1024 -> rowptr + bsum
__global__ __launch_bounds__(256) void k_scan1(const int* __restrict__ partial,
                                               int* __restrict__ rowptr,
                                               int* __restrict__ bsum, int n) {
  __shared__ int wsum[4];
  int base = blockIdx.x * 1024 + threadIdx.x * 4;
  int4 v = make_int4(0, 0, 0, 0);
  if (base + 3 < n) {
#pragma unroll
    for (int c = 0; c < NC; ++c) {
      int4 t = *(const int4*)(partial + (size_t)c * n + base);
      v.x += t.x; v.y += t.y; v.z += t.z; v.w += t.w;
    }
  } else {
#pragma unroll
    for (int c = 0; c < NC; ++c) {
      const int* pc = partial + (size_t)c * n;
      if (base + 0 < n) v.x += pc[base + 0];
      if (base + 1 < n) v.y += pc[base + 1];
      if (base + 2 < n) v.z += pc[base + 2];
      if (base + 3 < n) v.w += pc[base + 3];
    }
  }
  int s = v.x + v.y + v.z + v.w;
  int lane = threadIdx.x & 63;
  int wave = threadIdx.x >> 6;
  int incl = s;
#pragma unroll
  for (int off = 1; off < 64; off <<= 1) {
    int t = __shfl_up(incl, off);
    if (lane >= off) incl += t;
  }
  if (lane == 63) wsum[wave] = incl;
  __syncthreads();
  int woff = 0;
#pragma unroll
  for (int w = 0; w < 4; ++w) if (w < wave) woff += wsum[w];
  int excl = woff + incl - s;
  if (base + 0 < n) rowptr[base + 0] = excl;
  if (base + 1 < n) rowptr[base + 1] = excl + v.x;
  if (base + 2 < n) rowptr[base + 2] = excl + v.x + v.y;
  if (base + 3 < n) rowptr[base + 3] = excl + v.x + v.y + v.z;
  if (threadIdx.x == 255) bsum[blockIdx.x] = woff + incl;
}

// cursors (scan2 fused): wave 0 scans bsum; finalize rowptr; cursor[c][t] bases
__global__ __launch_bounds__(256) void k_cursors(int* __restrict__ rowptr,
                                                 const int* __restrict__ bsum,
                                                 const int* __restrict__ partial,
                                                 int* __restrict__ cursor,
                                                 int n, int E, int nb) {
  __shared__ int bpre_s[64];
  if (threadIdx.x < 64) {
    int lane = threadIdx.x;
    int v = (lane < nb) ? bsum[lane] : 0;
    int incl = v;
#pragma unroll
    for (int off = 1; off < 64; off <<= 1) {
      int t = __shfl_up(incl, off);
      if (lane >= off) incl += t;
    }
    bpre_s[lane] = incl - v;
  }
  __syncthreads();
  int t = blockIdx.x * blockDim.x + threadIdx.x;
  if (t < n) {
    int r = rowptr[t] + bpre_s[t >> 10];
    rowptr[t] = r;
#pragma unroll
    for (int c = 0; c < NC; ++c) {
      cursor[c * n + t] = r;
      r += partial[c * n + t];
    }
  }
  if (t == 0) rowptr[n] = E;
}

// fill (NO returning atomics): ew = sigmoid(p[s]+q[t]+b);
// edata[cursor_base+rank] = (src:u16 | bf16(ew)<<16)  -- 4B packed record
// degw[t] += ew via fire-and-forget float atomic (no return wait) so the
// MFMA kernel never has to re-walk edata for the degree sum.
__global__ __launch_bounds__(256) void k_fill(const int* __restrict__ src,
                                              const int* __restrict__ tgt,
                                              const int* __restrict__ rank,
                                              const int* __restrict__ cursor,
                                              const float* __restrict__ p,
                                              const float* __restrict__ q,
                                              const float* __restrict__ b_pred,
                                              unsigned int* __restrict__ edata,
                                              float* __restrict__ degw,
                                              int E, int n) {
  int e = blockIdx.x * blockDim.x + threadIdx.x;
  if (e >= E) return;
  int s = src[e], t = tgt[e];
  int c = (e >> 8) & (NC - 1);
  int pos = cursor[c * n + t] + rank[e];
  float z = p[s] + q[t] + b_pred[0];
  float w = 1.0f / (1.0f + expf(-z));
  edata[pos] = (unsigned int)s | (bf16_round(w) << 16);  // n < 65536 fits u16
  atomicAdd(&degw[t], w);  // non-returning, pipelined
}

// MFMA GEMM + fused dis: dis[row] = rsqrt(1 + degw[row]) (precomputed sum, no
// per-row seg-sum latency chain), then xwh = bf16( dis[row] * (xbh @ W) ).
__global__ __launch_bounds__(256) void k_gemm_mfma(const short* __restrict__ xbh,
                                                   const short* __restrict__ wt,
                                                   const float* __restrict__ degw,
                                                   float* __restrict__ dis,
                                                   unsigned int* __restrict__ xwh, int n) {
  __shared__ float cbuf[4][16 * 128];  // 32 KB
  int wave = threadIdx.x >> 6;
  int lane = threadIdx.x & 63;
  int row0 = blockIdx.x * 64 + wave * 16;

  // ---- dis for this wave's 16 rows (broadcast 4 B read per row) ----
  int rr = lane >> 2, jj = lane & 3;
  int grow = row0 + rr;
  float dv = 0.0f;
  if (grow < n) {
    float d = 1.0f + degw[grow];
    dv = (d > 0.0f) ? rsqrtf(d) : 0.0f;
    if (jj == 0) dis[grow] = dv;
  }

  // ---- MFMA ----
  int rA = lane & 15, quad = lane >> 4;
  f32x4 acc[8];
#pragma unroll
  for (int cb = 0; cb < 8; ++cb) acc[cb] = (f32x4){0.f, 0.f, 0.f, 0.f};

  const short* arow = xbh + (size_t)(row0 + rA) * 128 + quad * 8;
  bool arow_ok = (row0 + rA) < n;
#pragma unroll
  for (int kk = 0; kk < 4; ++kk) {
    bf16x8 a;
    if (arow_ok) a = *(const bf16x8*)(arow + kk * 32);
    else a = (bf16x8){0, 0, 0, 0, 0, 0, 0, 0};
#pragma unroll
    for (int cb = 0; cb < 8; ++cb) {
      bf16x8 bf = *(const bf16x8*)(wt + (size_t)(cb * 16 + rA) * 128 + kk * 32 + quad * 8);
      acc[cb] = __builtin_amdgcn_mfma_f32_16x16x32_bf16(a, bf, acc[cb], 0, 0, 0);
    }
  }

  // C/D layout: col = cb*16 + (lane&15), row = quad*4 + reg
#pragma unroll
  for (int cb = 0; cb < 8; ++cb)
#pragma unroll
    for (int r = 0; r < 4; ++r)
      cbuf[wave][(quad * 4 + r) * 128 + cb * 16 + rA] = acc[cb][r];
  __syncthreads();

  int ch = jj * 32;                // col chunk of 32 (jj = lane&3)
  if (grow < n) {
    const float* cr = &cbuf[wave][rr * 128 + ch];
#pragma unroll
    for (int g = 0; g < 2; ++g) {  // 2 x 16 cols -> 2 x uint4
      uint4 o;
      o.x = bf16_round(cr[g * 16 + 0] * dv)  | (bf16_round(cr[g * 16 + 1] * dv) << 16);
      o.y = bf16_round(cr[g * 16 + 2] * dv)  | (bf16_round(cr[g * 16 + 3] * dv) << 16);
      o.z = bf16_round(cr[g * 16 + 4] * dv)  | (bf16_round(cr[g * 16 + 5] * dv) << 16);
      o.w = bf16_round(cr[g * 16 + 6] * dv)  | (bf16_round(cr[g * 16 + 7] * dv) << 16);
      uint4 o2;
      o2.x = bf16_round(cr[g * 16 + 8] * dv)  | (bf16_round(cr[g * 16 + 9] * dv) << 16);
      o2.y = bf16_round(cr[g * 16 + 10] * dv) | (bf16_round(cr[g * 16 + 11] * dv) << 16);
      o2.z = bf16_round(cr[g * 16 + 12] * dv) | (bf16_round(cr[g * 16 + 13] * dv) << 16);
      o2.w = bf16_round(cr[g * 16 + 14] * dv) | (bf16_round(cr[g * 16 + 15] * dv) << 16);
      *(uint4*)(xwh + (size_t)grow * 64 + (ch >> 1) + g * 8)     = o;
      *(uint4*)(xwh + (size_t)grow * 64 + (ch >> 1) + g * 8 + 4) = o2;
    }
  }
}

// One wave per node; lane = (rg in [0,4), cj in [0,16)). ILP-batched: per
// 16-edge group, all 4 shuffle-extracts and all 4 scattered uint4 loads issue
// before the FMA block (R11 profile showed VGPR=20 -> serial load-use chain).
__global__ __launch_bounds__(256) void k_gather(const int* __restrict__ rowptr,
                                                const unsigned int* __restrict__ edata,
                                                const uint4* __restrict__ xwh4,
                                                const float* __restrict__ dis,
                                                const float* __restrict__ b,
                                                float* __restrict__ out, int n) {
  int wid = (blockIdx.x * blockDim.x + threadIdx.x) >> 6;
  int lane = threadIdx.x & 63;
  if (wid >= n) return;
  int cj = lane & 15;
  int rg = lane >> 4;
  int2 rp = *(const int2*)(rowptr + wid);
  int beg = rp.x, end = rp.y;

  float acc[8];
  if (rg == 0) {  // self-loop term, counted once
    uint4 v = xwh4[(size_t)wid * 16 + cj];
    acc[0] = bf_lo(v.x); acc[1] = bf_hi(v.x);
    acc[2] = bf_lo(v.y); acc[3] = bf_hi(v.y);
    acc[4] = bf_lo(v.z); acc[5] = bf_hi(v.z);
    acc[6] = bf_lo(v.w); acc[7] = bf_hi(v.w);
  } else {
#pragma unroll
    for (int i = 0; i < 8; ++i) acc[i] = 0.0f;
  }

  for (int j0 = beg; j0 < end; j0 += 64) {
    int m = end - j0; if (m > 64) m = 64;
    unsigned int wl = 0;
    if (lane < m) wl = edata[j0 + lane];
    for (int k = 0; k < m; k += 16) {
      // extract 4 records (independent shfls), zero-guard tails
      unsigned int w0 = (unsigned int)__shfl((int)wl, k + rg);
      unsigned int w1 = (unsigned int)__shfl((int)wl, k + 4 + rg);
      unsigned int w2 = (unsigned int)__shfl((int)wl, k + 8 + rg);
      unsigned int w3 = (unsigned int)__shfl((int)wl, k + 12 + rg);
      if (k + rg >= m)      w0 = 0;  // s=0, c=+0.0 -> harmless
      if (k + 4 + rg >= m)  w1 = 0;
      if (k + 8 + rg >= m)  w2 = 0;
      if (k + 12 + rg >= m) w3 = 0;
      // issue all 4 scattered loads back-to-back (overlapping latencies)
      uint4 v0 = xwh4[(size_t)(w0 & 0xffffu) * 16 + cj];
      uint4 v1 = xwh4[(size_t)(w1 & 0xffffu) * 16 + cj];
      uint4 v2 = xwh4[(size_t)(w2 & 0xffffu) * 16 + cj];
      uint4 v3 = xwh4[(size_t)(w3 & 0xffffu) * 16 + cj];
      float c0 = bf_hi(w0), c1 = bf_hi(w1), c2 = bf_hi(w2), c3 = bf_hi(w3);
      acc[0] = fmaf(c0, bf_lo(v0.x), acc[0]); acc[1] = fmaf(c0, bf_hi(v0.x), acc[1]);
      acc[2] = fmaf(c0, bf_lo(v0.y), acc[2]); acc[3] = fmaf(c0, bf_hi(v0.y), acc[3]);
      acc[4] = fmaf(c0, bf_lo(v0.z), acc[4]); acc[5] = fmaf(c0, bf_hi(v0.z), acc[5]);
      acc[6] = fmaf(c0, bf_lo(v0.w), acc[6]); acc[7] = fmaf(c0, bf_hi(v0.w), acc[7]);
      acc[0] = fmaf(c1, bf_lo(v1.x), acc[0]); acc[1] = fmaf(c1, bf_hi(v1.x), acc[1]);
      acc[2] = fmaf(c1, bf_lo(v1.y), acc[2]); acc[3] = fmaf(c1, bf_hi(v1.y), acc[3]);
      acc[4] = fmaf(c1, bf_lo(v1.z), acc[4]); acc[5] = fmaf(c1, bf_hi(v1.z), acc[5]);
      acc[6] = fmaf(c1, bf_lo(v1.w), acc[6]); acc[7] = fmaf(c1, bf_hi(v1.w), acc[7]);
      acc[0] = fmaf(c2, bf_lo(v2.x), acc[0]); acc[1] = fmaf(c2, bf_hi(v2.x), acc[1]);
      acc[2] = fmaf(c2, bf_lo(v2.y), acc[2]); acc[3] = fmaf(c2, bf_hi(v2.y), acc[3]);
      acc[4] = fmaf(c2, bf_lo(v2.z), acc[4]); acc[5] = fmaf(c2, bf_hi(v2.z), acc[5]);
      acc[6] = fmaf(c2, bf_lo(v2.w), acc[6]); acc[7] = fmaf(c2, bf_hi(v2.w), acc[7]);
      acc[0] = fmaf(c3, bf_lo(v3.x), acc[0]); acc[1] = fmaf(c3, bf_hi(v3.x), acc[1]);
      acc[2] = fmaf(c3, bf_lo(v3.y), acc[2]); acc[3] = fmaf(c3, bf_hi(v3.y), acc[3]);
      acc[4] = fmaf(c3, bf_lo(v3.z), acc[4]); acc[5] = fmaf(c3, bf_hi(v3.z), acc[5]);
      acc[6] = fmaf(c3, bf_lo(v3.w), acc[6]); acc[7] = fmaf(c3, bf_hi(v3.w), acc[7]);
    }
  }

#pragma unroll
  for (int i = 0; i < 8; ++i) {
    acc[i] += __shfl_xor(acc[i], 16);
    acc[i] += __shfl_xor(acc[i], 32);
  }

  if (rg == 0) {
    float dt = dis[wid];
    float4 b0 = ((const float4*)b)[cj * 2];
    float4 b1 = ((const float4*)b)[cj * 2 + 1];
    float4 o0, o1;
    o0.x = fmaf(dt, acc[0], b0.x); o0.y = fmaf(dt, acc[1], b0.y);
    o0.z = fmaf(dt, acc[2], b0.z); o0.w = fmaf(dt, acc[3], b0.w);
    o1.x = fmaf(dt, acc[4], b1.x); o1.y = fmaf(dt, acc[5], b1.y);
    o1.z = fmaf(dt, acc[6], b1.z); o1.w = fmaf(dt, acc[7], b1.w);
    ((float4*)out)[(size_t)wid * 32 + cj * 2] = o0;
    ((float4*)out)[(size_t)wid * 32 + cj * 2 + 1] = o1;
  }
}

extern "C" void kernel_launch(void* const* d_in, const int* in_sizes, int n_in,
                              void* d_out, int out_size, void* d_ws, size_t ws_size,
                              hipStream_t stream) {
  const float* x      = (const float*)d_in[0];
  const int*   ei     = (const int*)d_in[1];
  const float* W      = (const float*)d_in[2];
  const float* b      = (const float*)d_in[3];
  const float* w_pred = (const float*)d_in[4];
  const float* b_pred = (const float*)d_in[5];

  int n = in_sizes[0] / D;
  int E = in_sizes[1] / 2;
  const int* src = ei;       // edge_index[0]
  const int* tgt = ei + E;   // edge_index[1]

  float* out = (float*)d_out;
  float* ws  = (float*)d_ws;
  // workspace layout (4B words)
  unsigned int* xwh = (unsigned int*)ws;           // n*64 (bf16 pairs)
  unsigned int* xbh = xwh + (size_t)n * 64;        // n*64 (bf16 pairs of x)
  float* p       = (float*)(xbh + (size_t)n * 64); // n
  float* q       = p + n;                          // n
  float* dis     = q + n;                          // n
  unsigned int* edata = (unsigned int*)(dis + n);  // E packed (src|ew)
  int*   rank    = (int*)(edata + E);              // E
  float* degw    = (float*)(rank + E);             // n   (zeroed, adjacent to partial)
  int*   partial = (int*)(degw + n);               // NC*n (zeroed)
  int*   cursor  = partial + (size_t)NC * n;       // NC*n
  int*   rowptr  = cursor + (size_t)NC * n;        // n+1
  int*   bsum    = rowptr + n + 1;                 // 64
  unsigned short* wt = (unsigned short*)(bsum + 64);  // 16384 shorts

  int nb = (n + 1023) / 1024;     // scan blocks (<=64 for n<=65536)
  int nbPq = (n + 3) / 4;
  int nbHist = (E + 255) / 256;
  int total = nbPq + nbHist;

  // zero degw + partial in one contiguous memset
  (void)hipMemsetAsync(degw, 0, ((size_t)NC * n + n) * sizeof(int), stream);
  k_pre<<<total, 256, 0, stream>>>(x, w_pred, W, tgt, p, q, xbh, wt, rank, partial,
                                   n, E, nbHist, total);
  k_scan1<<<nb, 256, 0, stream>>>(partial, rowptr, bsum, n);
  k_cursors<<<(n + 255) / 256, 256, 0, stream>>>(rowptr, bsum, partial, cursor, n, E, nb);
  k_fill<<<(E + 255) / 256, 256, 0, stream>>>(src, tgt, rank, cursor, p, q, b_pred,
                                              edata, degw, E, n);
  k_gemm_mfma<<<(n + 63) / 64, 256, 0, stream>>>((const short*)xbh, (const short*)wt,
                                                 degw, dis, xwh, n);
  k_gather<<<(n + 3) / 4, 256, 0, stream>>>(rowptr, edata, (const uint4*)xwh, dis, b, out, n);
}

// Round 3
// 193.107 us; speedup vs baseline: 1.3011x; 1.1695x over previous
//
#include <hip/hip_runtime.h>
#include <math.h>

#define D 128
#define NC 32   // privatized histogram copies

typedef __attribute__((ext_vector_type(8))) short bf16x8;
typedef __attribute__((ext_vector_type(4))) float f32x4;

__device__ __forceinline__ unsigned int bf16_round(float f) {
  unsigned int u = __float_as_uint(f);
  return (u + 0x7fffu + ((u >> 16) & 1u)) >> 16;  // RNE
}
__device__ __forceinline__ float bf_lo(unsigned int u) { return __uint_as_float(u << 16); }
__device__ __forceinline__ float bf_hi(unsigned int u) { return __uint_as_float(u & 0xffff0000u); }

// Fused role-split kernel (Bresenham-interleaved so both roles are co-resident):
//  - hist blocks: rank[e] = atomicAdd(partial[c][tgt[e]], 1)   (latency-bound,
//    hidden under the BW-bound pq role running on the same CUs)
//  - pq blocks:   p/q dots + xbh=bf16(x) + (first 64) wt=bf16(W^T)  (BW-bound)
__global__ __launch_bounds__(256) void k_pre(const float* __restrict__ x,
                                             const float* __restrict__ w_pred,
                                             const float* __restrict__ W,
                                             const int* __restrict__ tgt,
                                             float* __restrict__ p, float* __restrict__ q,
                                             unsigned int* __restrict__ xbh,
                                             unsigned short* __restrict__ wt,
                                             int* __restrict__ rank,
                                             int* __restrict__ partial,
                                             int n, int E, int nbHist, int total) {
  int bid = blockIdx.x;
  long long h0 = (long long)bid * nbHist / total;
  long long h1 = (long long)(bid + 1) * nbHist / total;
  if (h1 != h0) {
    // ---- hist role ----
    int e = (int)h0 * 256 + threadIdx.x;
    if (e < E) {
      int t = tgt[e];
      int c = (e >> 8) & (NC - 1);
      rank[e] = atomicAdd(&partial[c * n + t], 1);
    }
    return;
  }
  // ---- pq role ----
  int pqIdx = bid - (int)h1;
  int ptid = pqIdx * 256 + threadIdx.x;
  if (ptid < 16384) {  // W transpose -> bf16 (first 64 pq blocks)
    int col = ptid >> 7, k = ptid & 127;
    wt[col * 128 + k] = (unsigned short)bf16_round(W[k * 128 + col]);
  }
  int wid = ptid >> 6;
  int lane = threadIdx.x & 63;
  if (wid >= n) return;
  float2 xv = ((const float2*)(x + (size_t)wid * D))[lane];
  xbh[(size_t)wid * 64 + lane] = bf16_round(xv.x) | (bf16_round(xv.y) << 16);
  float2 wp = ((const float2*)w_pred)[lane];
  float2 wq = ((const float2*)w_pred)[64 + lane];
  float pp = xv.x * wp.x + xv.y * wp.y;
  float qq = xv.x * wq.x + xv.y * wq.y;
#pragma unroll
  for (int off = 32; off > 0; off >>= 1) {
    pp += __shfl_down(pp, off);
    qq += __shfl_down(qq, off);
  }
  if (lane == 0) { p[wid] = pp; q[wid] = qq; }
}

// scan1 (fused reduce): cnt[t]=sum_c partial[c][t]; block-scan 1024 -> rowptr + bsum
__global__ __launch_bounds__(256) void k_scan1(const int* __restrict__ partial,
                                               int* __restrict__ rowptr,
                                               int* __restrict__ bsum, int n) {
  __shared__ int wsum[4];
  int base = blockIdx.x * 1024 + threadIdx.x * 4;
  int4 v = make_int4(0, 0, 0, 0);
  if (base + 3 < n) {
#pragma unroll
    for (int c = 0; c < NC; ++c) {
      int4 t = *(const int4*)(partial + (size_t)c * n + base);
      v.x += t.x; v.y += t.y; v.z += t.z; v.w += t.w;
    }
  } else {
#pragma unroll
    for (int c = 0; c < NC; ++c) {
      const int* pc = partial + (size_t)c * n;
      if (base + 0 < n) v.x += pc[base + 0];
      if (base + 1 < n) v.y += pc[base + 1];
      if (base + 2 < n) v.z += pc[base + 2];
      if (base + 3 < n) v.w += pc[base + 3];
    }
  }
  int s = v.x + v.y + v.z + v.w;
  int lane = threadIdx.x & 63;
  int wave = threadIdx.x >> 6;
  int incl = s;
#pragma unroll
  for (int off = 1; off < 64; off <<= 1) {
    int t = __shfl_up(incl, off);
    if (lane >= off) incl += t;
  }
  if (lane == 63) wsum[wave] = incl;
  __syncthreads();
  int woff = 0;
#pragma unroll
  for (int w = 0; w < 4; ++w) if (w < wave) woff += wsum[w];
  int excl = woff + incl - s;
  if (base + 0 < n) rowptr[base + 0] = excl;
  if (base + 1 < n) rowptr[base + 1] = excl + v.x;
  if (base + 2 < n) rowptr[base + 2] = excl + v.x + v.y;
  if (base + 3 < n) rowptr[base + 3] = excl + v.x + v.y + v.z;
  if (threadIdx.x == 255) bsum[blockIdx.x] = woff + incl;
}

// cursors (scan2 fused): wave 0 scans bsum; finalize rowptr; cursor[c][t] bases
__global__ __launch_bounds__(256) void k_cursors(int* __restrict__ rowptr,
                                                 const int* __restrict__ bsum,
                                                 const int* __restrict__ partial,
                                                 int* __restrict__ cursor,
                                                 int n, int E, int nb) {
  __shared__ int bpre_s[64];
  if (threadIdx.x < 64) {
    int lane = threadIdx.x;
    int v = (lane < nb) ? bsum[lane] : 0;
    int incl = v;
#pragma unroll
    for (int off = 1; off < 64; off <<= 1) {
      int t = __shfl_up(incl, off);
      if (lane >= off) incl += t;
    }
    bpre_s[lane] = incl - v;
  }
  __syncthreads();
  int t = blockIdx.x * blockDim.x + threadIdx.x;
  if (t < n) {
    int r = rowptr[t] + bpre_s[t >> 10];
    rowptr[t] = r;
#pragma unroll
    for (int c = 0; c < NC; ++c) {
      cursor[c * n + t] = r;
      r += partial[c * n + t];
    }
  }
  if (t == 0) rowptr[n] = E;
}

// Fused fill + GEMM (Bresenham role-split; no data dependence between roles):
//  - fill role (latency-bound): ew = sigmoid(p[s]+q[t]+b);
//      edata[cursor_base+rank] = (src:u16 | bf16(ew)<<16)
//  - gemm role (BW/MFMA-bound): xwh = bf16( xbh @ W )  -- UNSCALED (dis folded
//    in at gather time), which is what removes the fill->gemm dependency.
__global__ __launch_bounds__(256) void k_fg(const int* __restrict__ src,
                                            const int* __restrict__ tgt,
                                            const int* __restrict__ rank,
                                            const int* __restrict__ cursor,
                                            const float* __restrict__ p,
                                            const float* __restrict__ q,
                                            const float* __restrict__ b_pred,
                                            unsigned int* __restrict__ edata,
                                            const short* __restrict__ xbh,
                                            const short* __restrict__ wt,
                                            unsigned int* __restrict__ xwh,
                                            int E, int n, int nbFill, int total) {
  __shared__ float cbuf[4][16 * 128];  // 32 KB (gemm role only)
  int bid = blockIdx.x;
  long long h0 = (long long)bid * nbFill / total;
  long long h1 = (long long)(bid + 1) * nbFill / total;
  if (h1 != h0) {
    // ---- fill role ----
    int e = (int)h0 * 256 + threadIdx.x;
    if (e < E) {
      int s = src[e], t = tgt[e];
      int c = (e >> 8) & (NC - 1);
      int pos = cursor[c * n + t] + rank[e];
      float z = p[s] + q[t] + b_pred[0];
      float w = 1.0f / (1.0f + expf(-z));
      edata[pos] = (unsigned int)s | (bf16_round(w) << 16);  // n < 65536 fits u16
    }
    return;
  }
  // ---- gemm role ----
  int gIdx = bid - (int)h1;
  int wave = threadIdx.x >> 6;
  int lane = threadIdx.x & 63;
  int row0 = gIdx * 64 + wave * 16;

  int rA = lane & 15, quad = lane >> 4;
  f32x4 acc[8];
#pragma unroll
  for (int cb = 0; cb < 8; ++cb) acc[cb] = (f32x4){0.f, 0.f, 0.f, 0.f};

  const short* arow = xbh + (size_t)(row0 + rA) * 128 + quad * 8;
  bool arow_ok = (row0 + rA) < n;
#pragma unroll
  for (int kk = 0; kk < 4; ++kk) {
    bf16x8 a;
    if (arow_ok) a = *(const bf16x8*)(arow + kk * 32);
    else a = (bf16x8){0, 0, 0, 0, 0, 0, 0, 0};
#pragma unroll
    for (int cb = 0; cb < 8; ++cb) {
      bf16x8 bf = *(const bf16x8*)(wt + (size_t)(cb * 16 + rA) * 128 + kk * 32 + quad * 8);
      acc[cb] = __builtin_amdgcn_mfma_f32_16x16x32_bf16(a, bf, acc[cb], 0, 0, 0);
    }
  }

  // C/D layout: col = cb*16 + (lane&15), row = quad*4 + reg
#pragma unroll
  for (int cb = 0; cb < 8; ++cb)
#pragma unroll
    for (int r = 0; r < 4; ++r)
      cbuf[wave][(quad * 4 + r) * 128 + cb * 16 + rA] = acc[cb][r];
  __syncthreads();

  int rr = lane >> 2, jj = lane & 3;
  int grow = row0 + rr;
  int ch = jj * 32;                // col chunk of 32 (jj = lane&3)
  if (grow < n) {
    const float* cr = &cbuf[wave][rr * 128 + ch];
#pragma unroll
    for (int g = 0; g < 2; ++g) {  // 2 x 16 cols -> 2 x uint4
      uint4 o;
      o.x = bf16_round(cr[g * 16 + 0])  | (bf16_round(cr[g * 16 + 1]) << 16);
      o.y = bf16_round(cr[g * 16 + 2])  | (bf16_round(cr[g * 16 + 3]) << 16);
      o.z = bf16_round(cr[g * 16 + 4])  | (bf16_round(cr[g * 16 + 5]) << 16);
      o.w = bf16_round(cr[g * 16 + 6])  | (bf16_round(cr[g * 16 + 7]) << 16);
      uint4 o2;
      o2.x = bf16_round(cr[g * 16 + 8])  | (bf16_round(cr[g * 16 + 9]) << 16);
      o2.y = bf16_round(cr[g * 16 + 10]) | (bf16_round(cr[g * 16 + 11]) << 16);
      o2.z = bf16_round(cr[g * 16 + 12]) | (bf16_round(cr[g * 16 + 13]) << 16);
      o2.w = bf16_round(cr[g * 16 + 14]) | (bf16_round(cr[g * 16 + 15]) << 16);
      *(uint4*)(xwh + (size_t)grow * 64 + (ch >> 1) + g * 8)     = o;
      *(uint4*)(xwh + (size_t)grow * 64 + (ch >> 1) + g * 8 + 4) = o2;
    }
  }
}

// dis from sorted edata: 4 lanes per row, segmented sum of bf16 ew (contiguous)
__global__ __launch_bounds__(256) void k_dis(const int* __restrict__ rowptr,
                                             const unsigned int* __restrict__ edata,
                                             float* __restrict__ dis, int n) {
  int tid = blockIdx.x * 256 + threadIdx.x;
  int grow = tid >> 2;
  int jj = tid & 3;
  if (grow >= n) return;
  int beg = rowptr[grow], end = rowptr[grow + 1];
  float sum = 0.0f;
  for (int j = beg + jj; j < end; j += 4) sum += bf_hi(edata[j]);
  sum += __shfl_xor(sum, 1);
  sum += __shfl_xor(sum, 2);
  if (jj == 0) {
    float d = 1.0f + sum;
    dis[grow] = (d > 0.0f) ? rsqrtf(d) : 0.0f;
  }
}

// One wave per node; lane = (rg in [0,4), cj in [0,16)). ILP-batched; xwh is
// UNSCALED so each record's coefficient is ew * dis[s] (4B broadcast load,
// L2-resident 200KB table, issued alongside the uint4 gathers).
__global__ __launch_bounds__(256) void k_gather(const int* __restrict__ rowptr,
                                                const unsigned int* __restrict__ edata,
                                                const uint4* __restrict__ xwh4,
                                                const float* __restrict__ dis,
                                                const float* __restrict__ b,
                                                float* __restrict__ out, int n) {
  int wid = (blockIdx.x * blockDim.x + threadIdx.x) >> 6;
  int lane = threadIdx.x & 63;
  if (wid >= n) return;
  int cj = lane & 15;
  int rg = lane >> 4;
  float dt = dis[wid];  // ready: k_dis ran before us
  int2 rp = *(const int2*)(rowptr + wid);
  int beg = rp.x, end = rp.y;

  float acc[8];
  if (rg == 0) {  // self-loop term: dt * xw[t]  (final *dt gives dt^2 * xw[t])
    uint4 v = xwh4[(size_t)wid * 16 + cj];
    acc[0] = dt * bf_lo(v.x); acc[1] = dt * bf_hi(v.x);
    acc[2] = dt * bf_lo(v.y); acc[3] = dt * bf_hi(v.y);
    acc[4] = dt * bf_lo(v.z); acc[5] = dt * bf_hi(v.z);
    acc[6] = dt * bf_lo(v.w); acc[7] = dt * bf_hi(v.w);
  } else {
#pragma unroll
    for (int i = 0; i < 8; ++i) acc[i] = 0.0f;
  }

  for (int j0 = beg; j0 < end; j0 += 64) {
    int m = end - j0; if (m > 64) m = 64;
    unsigned int wl = 0;
    if (lane < m) wl = edata[j0 + lane];
    for (int k = 0; k < m; k += 16) {
      // extract 4 records (independent shfls), zero-guard tails
      unsigned int w0 = (unsigned int)__shfl((int)wl, k + rg);
      unsigned int w1 = (unsigned int)__shfl((int)wl, k + 4 + rg);
      unsigned int w2 = (unsigned int)__shfl((int)wl, k + 8 + rg);
      unsigned int w3 = (unsigned int)__shfl((int)wl, k + 12 + rg);
      if (k + rg >= m)      w0 = 0;  // s=0, c=+0.0 -> harmless
      if (k + 4 + rg >= m)  w1 = 0;
      if (k + 8 + rg >= m)  w2 = 0;
      if (k + 12 + rg >= m) w3 = 0;
      // issue all 4 scattered loads + 4 broadcast dis loads back-to-back
      uint4 v0 = xwh4[(size_t)(w0 & 0xffffu) * 16 + cj];
      uint4 v1 = xwh4[(size_t)(w1 & 0xffffu) * 16 + cj];
      uint4 v2 = xwh4[(size_t)(w2 & 0xffffu) * 16 + cj];
      uint4 v3 = xwh4[(size_t)(w3 & 0xffffu) * 16 + cj];
      float d0 = dis[w0 & 0xffffu];
      float d1 = dis[w1 & 0xffffu];
      float d2 = dis[w2 & 0xffffu];
      float d3 = dis[w3 & 0xffffu];
      float c0 = bf_hi(w0) * d0, c1 = bf_hi(w1) * d1;
      float c2 = bf_hi(w2) * d2, c3 = bf_hi(w3) * d3;
      acc[0] = fmaf(c0, bf_lo(v0.x), acc[0]); acc[1] = fmaf(c0, bf_hi(v0.x), acc[1]);
      acc[2] = fmaf(c0, bf_lo(v0.y), acc[2]); acc[3] = fmaf(c0, bf_hi(v0.y), acc[3]);
      acc[4] = fmaf(c0, bf_lo(v0.z), acc[4]); acc[5] = fmaf(c0, bf_hi(v0.z), acc[5]);
      acc[6] = fmaf(c0, bf_lo(v0.w), acc[6]); acc[7] = fmaf(c0, bf_hi(v0.w), acc[7]);
      acc[0] = fmaf(c1, bf_lo(v1.x), acc[0]); acc[1] = fmaf(c1, bf_hi(v1.x), acc[1]);
      acc[2] = fmaf(c1, bf_lo(v1.y), acc[2]); acc[3] = fmaf(c1, bf_hi(v1.y), acc[3]);
      acc[4] = fmaf(c1, bf_lo(v1.z), acc[4]); acc[5] = fmaf(c1, bf_hi(v1.z), acc[5]);
      acc[6] = fmaf(c1, bf_lo(v1.w), acc[6]); acc[7] = fmaf(c1, bf_hi(v1.w), acc[7]);
      acc[0] = fmaf(c2, bf_lo(v2.x), acc[0]); acc[1] = fmaf(c2, bf_hi(v2.x), acc[1]);
      acc[2] = fmaf(c2, bf_lo(v2.y), acc[2]); acc[3] = fmaf(c2, bf_hi(v2.y), acc[3]);
      acc[4] = fmaf(c2, bf_lo(v2.z), acc[4]); acc[5] = fmaf(c2, bf_hi(v2.z), acc[5]);
      acc[6] = fmaf(c2, bf_lo(v2.w), acc[6]); acc[7] = fmaf(c2, bf_hi(v2.w), acc[7]);
      acc[0] = fmaf(c3, bf_lo(v3.x), acc[0]); acc[1] = fmaf(c3, bf_hi(v3.x), acc[1]);
      acc[2] = fmaf(c3, bf_lo(v3.y), acc[2]); acc[3] = fmaf(c3, bf_hi(v3.y), acc[3]);
      acc[4] = fmaf(c3, bf_lo(v3.z), acc[4]); acc[5] = fmaf(c3, bf_hi(v3.z), acc[5]);
      acc[6] = fmaf(c3, bf_lo(v3.w), acc[6]); acc[7] = fmaf(c3, bf_hi(v3.w), acc[7]);
    }
  }

#pragma unroll
  for (int i = 0; i < 8; ++i) {
    acc[i] += __shfl_xor(acc[i], 16);
    acc[i] += __shfl_xor(acc[i], 32);
  }

  if (rg == 0) {
    float4 b0 = ((const float4*)b)[cj * 2];
    float4 b1 = ((const float4*)b)[cj * 2 + 1];
    float4 o0, o1;
    o0.x = fmaf(dt, acc[0], b0.x); o0.y = fmaf(dt, acc[1], b0.y);
    o0.z = fmaf(dt, acc[2], b0.z); o0.w = fmaf(dt, acc[3], b0.w);
    o1.x = fmaf(dt, acc[4], b1.x); o1.y = fmaf(dt, acc[5], b1.y);
    o1.z = fmaf(dt, acc[6], b1.z); o1.w = fmaf(dt, acc[7], b1.w);
    ((float4*)out)[(size_t)wid * 32 + cj * 2] = o0;
    ((float4*)out)[(size_t)wid * 32 + cj * 2 + 1] = o1;
  }
}

extern "C" void kernel_launch(void* const* d_in, const int* in_sizes, int n_in,
                              void* d_out, int out_size, void* d_ws, size_t ws_size,
                              hipStream_t stream) {
  const float* x      = (const float*)d_in[0];
  const int*   ei     = (const int*)d_in[1];
  const float* W      = (const float*)d_in[2];
  const float* b      = (const float*)d_in[3];
  const float* w_pred = (const float*)d_in[4];
  const float* b_pred = (const float*)d_in[5];

  int n = in_sizes[0] / D;
  int E = in_sizes[1] / 2;
  const int* src = ei;       // edge_index[0]
  const int* tgt = ei + E;   // edge_index[1]

  float* out = (float*)d_out;
  float* ws  = (float*)d_ws;
  // workspace layout (4B words)
  unsigned int* xwh = (unsigned int*)ws;           // n*64 (bf16 pairs, UNSCALED x@W)
  unsigned int* xbh = xwh + (size_t)n * 64;        // n*64 (bf16 pairs of x)
  float* p       = (float*)(xbh + (size_t)n * 64); // n
  float* q       = p + n;                          // n
  float* dis     = q + n;                          // n
  unsigned int* edata = (unsigned int*)(dis + n);  // E packed (src|ew)
  int*   rank    = (int*)(edata + E);              // E
  int*   partial = rank + E;                       // NC*n (zeroed)
  int*   cursor  = partial + (size_t)NC * n;       // NC*n
  int*   rowptr  = cursor + (size_t)NC * n;        // n+1
  int*   bsum    = rowptr + n + 1;                 // 64
  unsigned short* wt = (unsigned short*)(bsum + 64);  // 16384 shorts

  int nb = (n + 1023) / 1024;     // scan blocks (<=64 for n<=65536)
  int nbPq = (n + 3) / 4;
  int nbHist = (E + 255) / 256;
  int totalPre = nbPq + nbHist;

  int nbFill = (E + 255) / 256;
  int nbGemm = (n + 63) / 64;
  int totalFg = nbFill + nbGemm;

  (void)hipMemsetAsync(partial, 0, (size_t)NC * n * sizeof(int), stream);
  k_pre<<<totalPre, 256, 0, stream>>>(x, w_pred, W, tgt, p, q, xbh, wt, rank, partial,
                                      n, E, nbHist, totalPre);
  k_scan1<<<nb, 256, 0, stream>>>(partial, rowptr, bsum, n);
  k_cursors<<<(n + 255) / 256, 256, 0, stream>>>(rowptr, bsum, partial, cursor, n, E, nb);
  k_fg<<<totalFg, 256, 0, stream>>>(src, tgt, rank, cursor, p, q, b_pred, edata,
                                    (const short*)xbh, (const short*)wt, xwh,
                                    E, n, nbFill, totalFg);
  k_dis<<<(4 * n + 255) / 256, 256, 0, stream>>>(rowptr, edata, dis, n);
  k_gather<<<(n + 3) / 4, 256, 0, stream>>>(rowptr, edata, (const uint4*)xwh, dis, b, out, n);
}

// Round 4
// 189.765 us; speedup vs baseline: 1.3240x; 1.0176x over previous
//
#include <hip/hip_runtime.h>
#include <math.h>

#define D 128
#define NC 32   // privatized histogram copies

typedef __attribute__((ext_vector_type(8))) short bf16x8;
typedef __attribute__((ext_vector_type(4))) float f32x4;

__device__ __forceinline__ unsigned int bf16_round(float f) {
  unsigned int u = __float_as_uint(f);
  return (u + 0x7fffu + ((u >> 16) & 1u)) >> 16;  // RNE
}
__device__ __forceinline__ float bf_lo(unsigned int u) { return __uint_as_float(u << 16); }
__device__ __forceinline__ float bf_hi(unsigned int u) { return __uint_as_float(u & 0xffff0000u); }
__device__ __forceinline__ unsigned int pack2(float a, float b) {
  return bf16_round(a) | (bf16_round(b) << 16);
}

// Fused role-split kernel (Bresenham-interleaved so both roles are co-resident):
//  - hist blocks: rank[e]=atomicAdd(partial[c][tgt[e]],1), 4 edges/thread (ILP-4
//    on the returning-atomic latency chain)
//  - pq blocks:   p/q dots + xbh=bf16(x) + (first 64) wt=bf16(W^T)  (BW-bound)
__global__ __launch_bounds__(256) void k_pre(const float* __restrict__ x,
                                             const float* __restrict__ w_pred,
                                             const float* __restrict__ W,
                                             const int* __restrict__ tgt,
                                             float* __restrict__ p, float* __restrict__ q,
                                             unsigned int* __restrict__ xbh,
                                             unsigned short* __restrict__ wt,
                                             int* __restrict__ rank,
                                             int* __restrict__ partial,
                                             int n, int E, int nbHist, int total) {
  int bid = blockIdx.x;
  long long h0 = (long long)bid * nbHist / total;
  long long h1 = (long long)(bid + 1) * nbHist / total;
  if (h1 != h0) {
    // ---- hist role: 1024 edges/block, 4/thread ----
    int e0 = (int)h0 * 1024 + threadIdx.x * 4;
    if (e0 + 3 < E) {
      int4 t4 = *(const int4*)(tgt + e0);
      int c = (e0 >> 8) & (NC - 1);   // e0..e0+3 share e>>8 (4-aligned in 256 chunk)
      int* pc = partial + (size_t)c * n;
      int r0 = atomicAdd(&pc[t4.x], 1);
      int r1 = atomicAdd(&pc[t4.y], 1);
      int r2 = atomicAdd(&pc[t4.z], 1);
      int r3 = atomicAdd(&pc[t4.w], 1);
      *(int4*)(rank + e0) = make_int4(r0, r1, r2, r3);
    } else {
#pragma unroll
      for (int i = 0; i < 4; ++i) {
        int e = e0 + i;
        if (e < E) {
          int t = tgt[e];
          int c = (e >> 8) & (NC - 1);
          rank[e] = atomicAdd(&partial[(size_t)c * n + t], 1);
        }
      }
    }
    return;
  }
  // ---- pq role ----
  int pqIdx = bid - (int)h1;
  int ptid = pqIdx * 256 + threadIdx.x;
  if (ptid < 16384) {  // W transpose -> bf16 (first 64 pq blocks)
    int col = ptid >> 7, k = ptid & 127;
    wt[col * 128 + k] = (unsigned short)bf16_round(W[k * 128 + col]);
  }
  int wid = ptid >> 6;
  int lane = threadIdx.x & 63;
  if (wid >= n) return;
  float2 xv = ((const float2*)(x + (size_t)wid * D))[lane];
  xbh[(size_t)wid * 64 + lane] = bf16_round(xv.x) | (bf16_round(xv.y) << 16);
  float2 wp = ((const float2*)w_pred)[lane];
  float2 wq = ((const float2*)w_pred)[64 + lane];
  float pp = xv.x * wp.x + xv.y * wp.y;
  float qq = xv.x * wq.x + xv.y * wq.y;
#pragma unroll
  for (int off = 32; off > 0; off >>= 1) {
    pp += __shfl_down(pp, off);
    qq += __shfl_down(qq, off);
  }
  if (lane == 0) { p[wid] = pp; q[wid] = qq; }
}

// scan1 (fused reduce): cnt[t]=sum_c partial[c][t]; block-scan 1024 -> rowptr + bsum
__global__ __launch_bounds__(256) void k_scan1(const int* __restrict__ partial,
                                               int* __restrict__ rowptr,
                                               int* __restrict__ bsum, int n) {
  __shared__ int wsum[4];
  int base = blockIdx.x * 1024 + threadIdx.x * 4;
  int4 v = make_int4(0, 0, 0, 0);
  if (base + 3 < n) {
#pragma unroll
    for (int c = 0; c < NC; ++c) {
      int4 t = *(const int4*)(partial + (size_t)c * n + base);
      v.x += t.x; v.y += t.y; v.z += t.z; v.w += t.w;
    }
  } else {
#pragma unroll
    for (int c = 0; c < NC; ++c) {
      const int* pc = partial + (size_t)c * n;
      if (base + 0 < n) v.x += pc[base + 0];
      if (base + 1 < n) v.y += pc[base + 1];
      if (base + 2 < n) v.z += pc[base + 2];
      if (base + 3 < n) v.w += pc[base + 3];
    }
  }
  int s = v.x + v.y + v.z + v.w;
  int lane = threadIdx.x & 63;
  int wave = threadIdx.x >> 6;
  int incl = s;
#pragma unroll
  for (int off = 1; off < 64; off <<= 1) {
    int t = __shfl_up(incl, off);
    if (lane >= off) incl += t;
  }
  if (lane == 63) wsum[wave] = incl;
  __syncthreads();
  int woff = 0;
#pragma unroll
  for (int w = 0; w < 4; ++w) if (w < wave) woff += wsum[w];
  int excl = woff + incl - s;
  if (base + 0 < n) rowptr[base + 0] = excl;
  if (base + 1 < n) rowptr[base + 1] = excl + v.x;
  if (base + 2 < n) rowptr[base + 2] = excl + v.x + v.y;
  if (base + 3 < n) rowptr[base + 3] = excl + v.x + v.y + v.z;
  if (threadIdx.x == 255) bsum[blockIdx.x] = woff + incl;
}

// cursors (scan2 fused): wave 0 scans bsum; finalize rowptr; cursor[c][t] bases
__global__ __launch_bounds__(256) void k_cursors(int* __restrict__ rowptr,
                                                 const int* __restrict__ bsum,
                                                 const int* __restrict__ partial,
                                                 int* __restrict__ cursor,
                                                 int n, int E, int nb) {
  __shared__ int bpre_s[64];
  if (threadIdx.x < 64) {
    int lane = threadIdx.x;
    int v = (lane < nb) ? bsum[lane] : 0;
    int incl = v;
#pragma unroll
    for (int off = 1; off < 64; off <<= 1) {
      int t = __shfl_up(incl, off);
      if (lane >= off) incl += t;
    }
    bpre_s[lane] = incl - v;
  }
  __syncthreads();
  int t = blockIdx.x * blockDim.x + threadIdx.x;
  if (t < n) {
    int r = rowptr[t] + bpre_s[t >> 10];
    rowptr[t] = r;
#pragma unroll
    for (int c = 0; c < NC; ++c) {
      cursor[c * n + t] = r;
      r += partial[c * n + t];
    }
  }
  if (t == 0) rowptr[n] = E;
}

// Fused fill + GEMM (Bresenham role-split; no data dependence between roles):
//  - fill role (latency-bound, 4 edges/thread ILP): ew = sigmoid(p[s]+q[t]+b);
//      edata[cursor_base+rank] = (src:u16 | bf16(ew)<<16)
//  - gemm role (BW/MFMA-bound): xwh = bf16( xbh @ W )  -- UNSCALED.
//    Epilogue stages through 16KB per-wave LDS (two passes, no barrier) so
//    fill-role blocks get +1 CU co-residency vs the 32KB version.
__global__ __launch_bounds__(256) void k_fg(const int* __restrict__ src,
                                            const int* __restrict__ tgt,
                                            const int* __restrict__ rank,
                                            const int* __restrict__ cursor,
                                            const float* __restrict__ p,
                                            const float* __restrict__ q,
                                            const float* __restrict__ b_pred,
                                            unsigned int* __restrict__ edata,
                                            const short* __restrict__ xbh,
                                            const short* __restrict__ wt,
                                            unsigned int* __restrict__ xwh,
                                            int E, int n, int nbFill, int total) {
  __shared__ float cbuf[4][16 * 64];  // 16 KB (gemm role only; per-wave slices)
  int bid = blockIdx.x;
  long long h0 = (long long)bid * nbFill / total;
  long long h1 = (long long)(bid + 1) * nbFill / total;
  if (h1 != h0) {
    // ---- fill role: 1024 edges/block, 4/thread ----
    int e0 = (int)h0 * 1024 + threadIdx.x * 4;
    float bp = b_pred[0];
    if (e0 + 3 < E) {
      int4 s4 = *(const int4*)(src + e0);
      int4 t4 = *(const int4*)(tgt + e0);
      int4 r4 = *(const int4*)(rank + e0);
      int c = (e0 >> 8) & (NC - 1);
      const int* cc = cursor + (size_t)c * n;
      int pos0 = cc[t4.x] + r4.x;
      int pos1 = cc[t4.y] + r4.y;
      int pos2 = cc[t4.z] + r4.z;
      int pos3 = cc[t4.w] + r4.w;
      float z0 = p[s4.x] + q[t4.x] + bp;
      float z1 = p[s4.y] + q[t4.y] + bp;
      float z2 = p[s4.z] + q[t4.z] + bp;
      float z3 = p[s4.w] + q[t4.w] + bp;
      float w0 = 1.0f / (1.0f + expf(-z0));
      float w1 = 1.0f / (1.0f + expf(-z1));
      float w2 = 1.0f / (1.0f + expf(-z2));
      float w3 = 1.0f / (1.0f + expf(-z3));
      edata[pos0] = (unsigned int)s4.x | (bf16_round(w0) << 16);
      edata[pos1] = (unsigned int)s4.y | (bf16_round(w1) << 16);
      edata[pos2] = (unsigned int)s4.z | (bf16_round(w2) << 16);
      edata[pos3] = (unsigned int)s4.w | (bf16_round(w3) << 16);
    } else {
#pragma unroll
      for (int i = 0; i < 4; ++i) {
        int e = e0 + i;
        if (e < E) {
          int s = src[e], t = tgt[e];
          int c = (e >> 8) & (NC - 1);
          int pos = cursor[(size_t)c * n + t] + rank[e];
          float z = p[s] + q[t] + bp;
          float w = 1.0f / (1.0f + expf(-z));
          edata[pos] = (unsigned int)s | (bf16_round(w) << 16);
        }
      }
    }
    return;
  }
  // ---- gemm role ----
  int gIdx = bid - (int)h1;
  int wave = threadIdx.x >> 6;
  int lane = threadIdx.x & 63;
  int row0 = gIdx * 64 + wave * 16;

  int rA = lane & 15, quad = lane >> 4;
  f32x4 acc[8];
#pragma unroll
  for (int cb = 0; cb < 8; ++cb) acc[cb] = (f32x4){0.f, 0.f, 0.f, 0.f};

  const short* arow = xbh + (size_t)(row0 + rA) * 128 + quad * 8;
  bool arow_ok = (row0 + rA) < n;
#pragma unroll
  for (int kk = 0; kk < 4; ++kk) {
    bf16x8 a;
    if (arow_ok) a = *(const bf16x8*)(arow + kk * 32);
    else a = (bf16x8){0, 0, 0, 0, 0, 0, 0, 0};
#pragma unroll
    for (int cb = 0; cb < 8; ++cb) {
      bf16x8 bf = *(const bf16x8*)(wt + (size_t)(cb * 16 + rA) * 128 + kk * 32 + quad * 8);
      acc[cb] = __builtin_amdgcn_mfma_f32_16x16x32_bf16(a, bf, acc[cb], 0, 0, 0);
    }
  }

  // C/D layout: col = cb*16 + rA, row = quad*4 + r. Two-pass per-wave staging
  // (4 KB/wave slice): pass h covers cols [64h, 64h+64). DS ops are in-order
  // per wave, so no barrier is needed (same-wave lane exchange only).
  int rr = lane >> 2, jj = lane & 3;
  int grow = row0 + rr;
#pragma unroll
  for (int h = 0; h < 2; ++h) {
#pragma unroll
    for (int cb4 = 0; cb4 < 4; ++cb4) {
      int cb = h * 4 + cb4;
#pragma unroll
      for (int r = 0; r < 4; ++r)
        cbuf[wave][(quad * 4 + r) * 64 + cb4 * 16 + rA] = acc[cb][r];
    }
    if (grow < n) {
      const float* cr = &cbuf[wave][rr * 64 + jj * 16];
      uint4 o, o2;
      o.x  = pack2(cr[0],  cr[1]);  o.y  = pack2(cr[2],  cr[3]);
      o.z  = pack2(cr[4],  cr[5]);  o.w  = pack2(cr[6],  cr[7]);
      o2.x = pack2(cr[8],  cr[9]);  o2.y = pack2(cr[10], cr[11]);
      o2.z = pack2(cr[12], cr[13]); o2.w = pack2(cr[14], cr[15]);
      *(uint4*)(xwh + (size_t)grow * 64 + h * 32 + jj * 8)     = o;
      *(uint4*)(xwh + (size_t)grow * 64 + h * 32 + jj * 8 + 4) = o2;
    }
  }
}

// dis from sorted edata: 4 lanes per row, segmented sum of bf16 ew (contiguous)
__global__ __launch_bounds__(256) void k_dis(const int* __restrict__ rowptr,
                                             const unsigned int* __restrict__ edata,
                                             float* __restrict__ dis, int n) {
  int tid = blockIdx.x * 256 + threadIdx.x;
  int grow = tid >> 2;
  int jj = tid & 3;
  if (grow >= n) return;
  int beg = rowptr[grow], end = rowptr[grow + 1];
  float sum = 0.0f;
  for (int j = beg + jj; j < end; j += 4) sum += bf_hi(edata[j]);
  sum += __shfl_xor(sum, 1);
  sum += __shfl_xor(sum, 2);
  if (jj == 0) {
    float d = 1.0f + sum;
    dis[grow] = (d > 0.0f) ? rsqrtf(d) : 0.0f;
  }
}

// Gather: 4 rows per wave, one row per 16-lane group (rg). Each group has its
// own rowptr->edata->xwh dependence chain (ILP-4 across rows in the wave), all
// 64 lanes stage edata usefully, and no cross-group reduction is needed.
// Coefficient per record: ew * dis[s] (xwh is UNSCALED).
__global__ __launch_bounds__(256) void k_gather(const int* __restrict__ rowptr,
                                                const unsigned int* __restrict__ edata,
                                                const uint4* __restrict__ xwh4,
                                                const float* __restrict__ dis,
                                                const float* __restrict__ b,
                                                float* __restrict__ out, int n) {
  int gw = (blockIdx.x * blockDim.x + threadIdx.x) >> 6;  // global wave id
  int lane = threadIdx.x & 63;
  int rg = lane >> 4, cj = lane & 15;
  int row = gw * 4 + rg;
  bool valid = row < n;

  float dt = 0.0f;
  int beg = 0, end = 0;
  if (valid) {
    dt = dis[row];
    int2 rp = *(const int2*)(rowptr + row);
    beg = rp.x; end = rp.y;
  }

  float acc[8];
  if (valid) {  // self-loop term: dt * xw[row] (final *dt gives dt^2 * xw[row])
    uint4 v = xwh4[(size_t)row * 16 + cj];
    acc[0] = dt * bf_lo(v.x); acc[1] = dt * bf_hi(v.x);
    acc[2] = dt * bf_lo(v.y); acc[3] = dt * bf_hi(v.y);
    acc[4] = dt * bf_lo(v.z); acc[5] = dt * bf_hi(v.z);
    acc[6] = dt * bf_lo(v.w); acc[7] = dt * bf_hi(v.w);
  } else {
#pragma unroll
    for (int i = 0; i < 8; ++i) acc[i] = 0.0f;
  }

  for (int j0 = beg; j0 < end; j0 += 16) {
    int m = end - j0; if (m > 16) m = 16;
    unsigned int wl = (cj < m) ? edata[j0 + cj] : 0u;  // group stages 16 records
    for (int k = 0; k < m; k += 4) {
      // broadcast 4 records from this group's staging lanes
      unsigned int w0 = (unsigned int)__shfl((int)wl, rg * 16 + k + 0);
      unsigned int w1 = (unsigned int)__shfl((int)wl, rg * 16 + k + 1);
      unsigned int w2 = (unsigned int)__shfl((int)wl, rg * 16 + k + 2);
      unsigned int w3 = (unsigned int)__shfl((int)wl, rg * 16 + k + 3);
      if (k + 1 >= m) w1 = 0;  // s=0, c=+0.0 -> harmless
      if (k + 2 >= m) w2 = 0;
      if (k + 3 >= m) w3 = 0;
      // 4 scattered row-loads + 4 broadcast dis loads, issued back-to-back
      uint4 v0 = xwh4[(size_t)(w0 & 0xffffu) * 16 + cj];
      uint4 v1 = xwh4[(size_t)(w1 & 0xffffu) * 16 + cj];
      uint4 v2 = xwh4[(size_t)(w2 & 0xffffu) * 16 + cj];
      uint4 v3 = xwh4[(size_t)(w3 & 0xffffu) * 16 + cj];
      float d0 = dis[w0 & 0xffffu];
      float d1 = dis[w1 & 0xffffu];
      float d2 = dis[w2 & 0xffffu];
      float d3 = dis[w3 & 0xffffu];
      float c0 = bf_hi(w0) * d0, c1 = bf_hi(w1) * d1;
      float c2 = bf_hi(w2) * d2, c3 = bf_hi(w3) * d3;
      acc[0] = fmaf(c0, bf_lo(v0.x), acc[0]); acc[1] = fmaf(c0, bf_hi(v0.x), acc[1]);
      acc[2] = fmaf(c0, bf_lo(v0.y), acc[2]); acc[3] = fmaf(c0, bf_hi(v0.y), acc[3]);
      acc[4] = fmaf(c0, bf_lo(v0.z), acc[4]); acc[5] = fmaf(c0, bf_hi(v0.z), acc[5]);
      acc[6] = fmaf(c0, bf_lo(v0.w), acc[6]); acc[7] = fmaf(c0, bf_hi(v0.w), acc[7]);
      acc[0] = fmaf(c1, bf_lo(v1.x), acc[0]); acc[1] = fmaf(c1, bf_hi(v1.x), acc[1]);
      acc[2] = fmaf(c1, bf_lo(v1.y), acc[2]); acc[3] = fmaf(c1, bf_hi(v1.y), acc[3]);
      acc[4] = fmaf(c1, bf_lo(v1.z), acc[4]); acc[5] = fmaf(c1, bf_hi(v1.z), acc[5]);
      acc[6] = fmaf(c1, bf_lo(v1.w), acc[6]); acc[7] = fmaf(c1, bf_hi(v1.w), acc[7]);
      acc[0] = fmaf(c2, bf_lo(v2.x), acc[0]); acc[1] = fmaf(c2, bf_hi(v2.x), acc[1]);
      acc[2] = fmaf(c2, bf_lo(v2.y), acc[2]); acc[3] = fmaf(c2, bf_hi(v2.y), acc[3]);
      acc[4] = fmaf(c2, bf_lo(v2.z), acc[4]); acc[5] = fmaf(c2, bf_hi(v2.z), acc[5]);
      acc[6] = fmaf(c2, bf_lo(v2.w), acc[6]); acc[7] = fmaf(c2, bf_hi(v2.w), acc[7]);
      acc[0] = fmaf(c3, bf_lo(v3.x), acc[0]); acc[1] = fmaf(c3, bf_hi(v3.x), acc[1]);
      acc[2] = fmaf(c3, bf_lo(v3.y), acc[2]); acc[3] = fmaf(c3, bf_hi(v3.y), acc[3]);
      acc[4] = fmaf(c3, bf_lo(v3.z), acc[4]); acc[5] = fmaf(c3, bf_hi(v3.z), acc[5]);
      acc[6] = fmaf(c3, bf_lo(v3.w), acc[6]); acc[7] = fmaf(c3, bf_hi(v3.w), acc[7]);
    }
  }

  if (valid) {
    float4 b0 = ((const float4*)b)[cj * 2];
    float4 b1 = ((const float4*)b)[cj * 2 + 1];
    float4 o0, o1;
    o0.x = fmaf(dt, acc[0], b0.x); o0.y = fmaf(dt, acc[1], b0.y);
    o0.z = fmaf(dt, acc[2], b0.z); o0.w = fmaf(dt, acc[3], b0.w);
    o1.x = fmaf(dt, acc[4], b1.x); o1.y = fmaf(dt, acc[5], b1.y);
    o1.z = fmaf(dt, acc[6], b1.z); o1.w = fmaf(dt, acc[7], b1.w);
    ((float4*)out)[(size_t)row * 32 + cj * 2] = o0;
    ((float4*)out)[(size_t)row * 32 + cj * 2 + 1] = o1;
  }
}

extern "C" void kernel_launch(void* const* d_in, const int* in_sizes, int n_in,
                              void* d_out, int out_size, void* d_ws, size_t ws_size,
                              hipStream_t stream) {
  const float* x      = (const float*)d_in[0];
  const int*   ei     = (const int*)d_in[1];
  const float* W      = (const float*)d_in[2];
  const float* b      = (const float*)d_in[3];
  const float* w_pred = (const float*)d_in[4];
  const float* b_pred = (const float*)d_in[5];

  int n = in_sizes[0] / D;
  int E = in_sizes[1] / 2;
  const int* src = ei;       // edge_index[0]
  const int* tgt = ei + E;   // edge_index[1]

  float* out = (float*)d_out;
  float* ws  = (float*)d_ws;
  // workspace layout (4B words)
  unsigned int* xwh = (unsigned int*)ws;           // n*64 (bf16 pairs, UNSCALED x@W)
  unsigned int* xbh = xwh + (size_t)n * 64;        // n*64 (bf16 pairs of x)
  float* p       = (float*)(xbh + (size_t)n * 64); // n
  float* q       = p + n;                          // n
  float* dis     = q + n;                          // n
  unsigned int* edata = (unsigned int*)(dis + n);  // E packed (src|ew)
  int*   rank    = (int*)(edata + E);              // E
  int*   partial = rank + E;                       // NC*n (zeroed)
  int*   cursor  = partial + (size_t)NC * n;       // NC*n
  int*   rowptr  = cursor + (size_t)NC * n;        // n+1
  int*   bsum    = rowptr + n + 1;                 // 64
  unsigned short* wt = (unsigned short*)(bsum + 64);  // 16384 shorts

  int nb = (n + 1023) / 1024;     // scan blocks (<=64 for n<=65536)
  int nbPq = (n + 3) / 4;
  int nbHist = (E + 1023) / 1024;  // 4 edges/thread
  int totalPre = nbPq + nbHist;

  int nbFill = (E + 1023) / 1024;  // 4 edges/thread
  int nbGemm = (n + 63) / 64;
  int totalFg = nbFill + nbGemm;

  int wavesG = (n + 3) / 4;                 // 4 rows per wave
  int nbGather = (wavesG + 3) / 4;          // 4 waves per block

  (void)hipMemsetAsync(partial, 0, (size_t)NC * n * sizeof(int), stream);
  k_pre<<<totalPre, 256, 0, stream>>>(x, w_pred, W, tgt, p, q, xbh, wt, rank, partial,
                                      n, E, nbHist, totalPre);
  k_scan1<<<nb, 256, 0, stream>>>(partial, rowptr, bsum, n);
  k_cursors<<<(n + 255) / 256, 256, 0, stream>>>(rowptr, bsum, partial, cursor, n, E, nb);
  k_fg<<<totalFg, 256, 0, stream>>>(src, tgt, rank, cursor, p, q, b_pred, edata,
                                    (const short*)xbh, (const short*)wt, xwh,
                                    E, n, nbFill, totalFg);
  k_dis<<<(4 * n + 255) / 256, 256, 0, stream>>>(rowptr, edata, dis, n);
  k_gather<<<nbGather, 256, 0, stream>>>(rowptr, edata, (const uint4*)xwh, dis, b, out, n);
}